// Round 1
// 1101.076 us; speedup vs baseline: 1.9074x; 1.9074x over previous
//
#include <hip/hip_runtime.h>
#include <math.h>

#define B_   32
#define P_   196
#define F_   2048
#define E_   512
#define H_   512
#define V_   10000
#define T_   20
#define GSZ  8            // blocks per batch-element group (block s=0 doubles as leader)
#define NBLK (B_ * GSZ)   // 256 persistent blocks = 1 per CU (LDS-limited)

typedef unsigned short ushort_t;
typedef ushort_t u16x8 __attribute__((ext_vector_type(8)));
typedef ushort_t u16x2 __attribute__((ext_vector_type(2)));
typedef short    bf16x8 __attribute__((ext_vector_type(8)));
typedef float    f32x4  __attribute__((ext_vector_type(4)));

__device__ __forceinline__ ushort_t bf_rne(float x) {
    union { float f; unsigned u; } v; v.f = x;
    unsigned r = v.u + 0x7FFFu + ((v.u >> 16) & 1u);
    return (ushort_t)(r >> 16);
}
__device__ __forceinline__ float b2f(ushort_t u) {
    union { unsigned u; float f; } v; v.u = ((unsigned)u) << 16;
    return v.f;
}

// ---------------------------------------------------------------------------
// One-time conversion mega-kernel (1 node): bf16 converts / extracts /
// transposes / caption-gather. 13125 blocks x 256 thr.
// ---------------------------------------------------------------------------
__global__ __launch_bounds__(256)
void cvt_all_kernel(const float* __restrict__ feat, const float* __restrict__ enc_W,
                    const float* __restrict__ fc_W, const float* __restrict__ dec_W,
                    const float* __restrict__ W_ih, const float* __restrict__ W_hh,
                    const float* __restrict__ emb, const int* __restrict__ captions,
                    const float* __restrict__ b_ih, const float* __restrict__ b_hh,
                    ushort_t* __restrict__ featB, ushort_t* __restrict__ encWB,
                    ushort_t* __restrict__ fcWB, ushort_t* __restrict__ decWB,
                    ushort_t* __restrict__ WihCB, ushort_t* __restrict__ WihEB,
                    ushort_t* __restrict__ WhhT, ushort_t* __restrict__ XB,
                    float* __restrict__ bsum, float* __restrict__ zbuf)
{
    const int blk = blockIdx.x, tid = threadIdx.x;
    if (blk < 6272) {                       // featB flat
        size_t i = (size_t)blk * 2048 + tid * 8;
        float4 a = *(const float4*)&feat[i], b = *(const float4*)&feat[i + 4];
        u16x8 o; o[0]=bf_rne(a.x); o[1]=bf_rne(a.y); o[2]=bf_rne(a.z); o[3]=bf_rne(a.w);
        o[4]=bf_rne(b.x); o[5]=bf_rne(b.y); o[6]=bf_rne(b.z); o[7]=bf_rne(b.w);
        *(u16x8*)&featB[i] = o;
    } else if (blk < 6784) {                // encWB
        size_t i = (size_t)(blk - 6272) * 2048 + tid * 8;
        float4 a = *(const float4*)&enc_W[i], b = *(const float4*)&enc_W[i + 4];
        u16x8 o; o[0]=bf_rne(a.x); o[1]=bf_rne(a.y); o[2]=bf_rne(a.z); o[3]=bf_rne(a.w);
        o[4]=bf_rne(b.x); o[5]=bf_rne(b.y); o[6]=bf_rne(b.z); o[7]=bf_rne(b.w);
        *(u16x8*)&encWB[i] = o;
    } else if (blk < 9284) {                // fcWB
        size_t i = (size_t)(blk - 6784) * 2048 + tid * 8;
        float4 a = *(const float4*)&fc_W[i], b = *(const float4*)&fc_W[i + 4];
        u16x8 o; o[0]=bf_rne(a.x); o[1]=bf_rne(a.y); o[2]=bf_rne(a.z); o[3]=bf_rne(a.w);
        o[4]=bf_rne(b.x); o[5]=bf_rne(b.y); o[6]=bf_rne(b.z); o[7]=bf_rne(b.w);
        *(u16x8*)&fcWB[i] = o;
    } else if (blk < 9412) {                // decWB
        size_t i = (size_t)(blk - 9284) * 2048 + tid * 8;
        float4 a = *(const float4*)&dec_W[i], b = *(const float4*)&dec_W[i + 4];
        u16x8 o; o[0]=bf_rne(a.x); o[1]=bf_rne(a.y); o[2]=bf_rne(a.z); o[3]=bf_rne(a.w);
        o[4]=bf_rne(b.x); o[5]=bf_rne(b.y); o[6]=bf_rne(b.z); o[7]=bf_rne(b.w);
        *(u16x8*)&decWB[i] = o;
    } else if (blk < 11460) {               // WihCB = bf16(W_ih[:, 512:2560]) [2048][2048]
        int j = blk - 9412, f = tid * 8;
        const float* s = &W_ih[(size_t)j * 2560 + 512 + f];
        float4 a = *(const float4*)&s[0], b = *(const float4*)&s[4];
        u16x8 o; o[0]=bf_rne(a.x); o[1]=bf_rne(a.y); o[2]=bf_rne(a.z); o[3]=bf_rne(a.w);
        o[4]=bf_rne(b.x); o[5]=bf_rne(b.y); o[6]=bf_rne(b.z); o[7]=bf_rne(b.w);
        *(u16x8*)&WihCB[(size_t)j * 2048 + f] = o;
    } else if (blk < 11972) {               // WihEB = bf16(W_ih[:, 0:512]) [2048][512]
        size_t idx = (size_t)(blk - 11460) * 2048 + tid * 8;
        int j = (int)(idx >> 9), f = (int)(idx & 511);
        const float* s = &W_ih[(size_t)j * 2560 + f];
        float4 a = *(const float4*)&s[0], b = *(const float4*)&s[4];
        u16x8 o; o[0]=bf_rne(a.x); o[1]=bf_rne(a.y); o[2]=bf_rne(a.z); o[3]=bf_rne(a.w);
        o[4]=bf_rne(b.x); o[5]=bf_rne(b.y); o[6]=bf_rne(b.z); o[7]=bf_rne(b.w);
        *(u16x8*)&WihEB[idx] = o;
    } else if (blk < 12484) {               // WhhT[k][j] = bf16(W_hh[j][k]) [512][2048]
        int k = blk - 11972, j0 = tid * 8;
        u16x8 o;
#pragma unroll
        for (int q = 0; q < 8; q++) o[q] = bf_rne(W_hh[(size_t)(j0 + q) * 512 + k]);
        *(u16x8*)&WhhT[(size_t)k * 2048 + j0] = o;
    } else if (blk < 13124) {               // XB[m] = bf16(emb[captions]), m = t*32+b
        int m = blk - 12484;
        int tt = m >> 5, b = m & 31;
        int cap = captions[b * T_ + tt];
        int i = tid * 2;
        u16x2 o;
        o[0] = bf_rne(emb[(size_t)cap * 512 + i]);
        o[1] = bf_rne(emb[(size_t)cap * 512 + i + 1]);
        *(u16x2*)&XB[(size_t)m * 512 + i] = o;
    } else {                                // bsum + zbuf
        int i = tid * 8;
#pragma unroll
        for (int q = 0; q < 8; q++) {
            bsum[i + q] = b_ih[i + q] + b_hh[i + q];
            zbuf[i + q] = 0.f;
        }
    }
}

// ---------------------------------------------------------------------------
// bf16 MFMA GEMM: C[m,n] = A[m,:].B[n,:] + bias[n], A/B bf16 K-major.
// 128x128 tile, 4 waves, 4x4 of 16x16x32 MFMA per wave.
// mode 0: bf16 store.  mode 1: f32 store, crow=(m&31)*20+(m>>5), guard n<N.
// mode 2: f32 store plain.
// ---------------------------------------------------------------------------
__global__ __launch_bounds__(256)
void mfma_gemm_kernel(const ushort_t* __restrict__ A, const ushort_t* __restrict__ B,
                      const float* __restrict__ bias, ushort_t* __restrict__ Cb,
                      float* __restrict__ Cf, int K, int N, int mode)
{
    __shared__ ushort_t As[128][32];
    __shared__ ushort_t Bs[128][32];
    const int tid = threadIdx.x;
    const int m0 = blockIdx.x * 128, n0 = blockIdx.y * 128;
    const int wave = tid >> 6, lane = tid & 63;
    const int wm = (wave & 1) * 64, wn = (wave >> 1) * 64;
    const int lm = lane & 15, lk = (lane >> 4) * 8;

    f32x4 acc[4][4];
#pragma unroll
    for (int mt = 0; mt < 4; mt++)
#pragma unroll
        for (int nt = 0; nt < 4; nt++)
#pragma unroll
            for (int r = 0; r < 4; r++) acc[mt][nt][r] = 0.f;

    for (int k0 = 0; k0 < K; k0 += 32) {
#pragma unroll
        for (int i = 0; i < 2; i++) {
            int gi  = tid + i * 256;
            int row = gi >> 2;
            int gr  = (gi & 3) * 8;
            *(u16x8*)&As[row][gr] = *(const u16x8*)&A[(size_t)(m0 + row) * K + k0 + gr];
            int brow = n0 + row; if (brow >= N) brow = N - 1;
            *(u16x8*)&Bs[row][gr] = *(const u16x8*)&B[(size_t)brow * K + k0 + gr];
        }
        __syncthreads();
        bf16x8 af[4], bv[4];
#pragma unroll
        for (int mt = 0; mt < 4; mt++)
            af[mt] = *(const bf16x8*)&As[wm + mt * 16 + lm][lk];
#pragma unroll
        for (int nt = 0; nt < 4; nt++)
            bv[nt] = *(const bf16x8*)&Bs[wn + nt * 16 + lm][lk];
#pragma unroll
        for (int mt = 0; mt < 4; mt++)
#pragma unroll
            for (int nt = 0; nt < 4; nt++)
                acc[mt][nt] = __builtin_amdgcn_mfma_f32_16x16x32_bf16(
                    af[mt], bv[nt], acc[mt][nt], 0, 0, 0);
        __syncthreads();
    }

    const int rb = (lane >> 4) * 4;
#pragma unroll
    for (int nt = 0; nt < 4; nt++) {
        int n = n0 + wn + nt * 16 + lm;
        int nc = n < N ? n : N - 1;
        float bz = bias[nc];
#pragma unroll
        for (int mt = 0; mt < 4; mt++) {
            int mbase = m0 + wm + mt * 16 + rb;
#pragma unroll
            for (int r = 0; r < 4; r++) {
                float v = acc[mt][nt][r] + bz;
                int m = mbase + r;
                if (mode == 0) {
                    Cb[(size_t)m * N + n] = bf_rne(v);
                } else if (n < N) {
                    int crow = (mode == 1) ? ((m & 31) * 20 + (m >> 5)) : m;
                    Cf[(size_t)crow * N + n] = v;
                }
            }
        }
    }
}

// ---------------------------------------------------------------------------
// Per-b producer/consumer sync, monotonic counters. Poll RELAXED (+s_sleep
// backoff), one ACQUIRE load on exit for cross-XCD visibility.
// ---------------------------------------------------------------------------
__device__ __forceinline__ void wait_ge(unsigned* p, unsigned target) {
    if (threadIdx.x == 0) {
        while (__hip_atomic_load(p, __ATOMIC_RELAXED, __HIP_MEMORY_SCOPE_AGENT) < target)
            __builtin_amdgcn_s_sleep(1);
        (void)__hip_atomic_load(p, __ATOMIC_ACQUIRE, __HIP_MEMORY_SCOPE_AGENT);
    }
    __syncthreads();
}

// ---------------------------------------------------------------------------
// Persistent 20-step decoder. 256 blocks = 32 groups x 8 blocks (1 per CU).
// Each block of group b holds G[b][:, s*256 .. s*256+255] in LDS (100 KB,
// loaded ONCE) so the per-step alpha.G reduction never touches HBM again
// (was 25.6 MB/step from HBM = the 527 MB FETCH_SIZE).
// Block s=0 is also the leader: pointwise LSTM (c in regs), dec_proj,
// energies, softmax. Flags (per-b cache line): word0 = h-ready (value t+1),
// word1 = alpha-ready (value t+1); cnt counts 7 worker completions/step.
// blockIdx remap b=blk&31, s=blk>>5 puts all 8 blocks of b on one XCD
// (round-robin heuristic; perf-only) so WhhT/encPB/decWB stay L2-resident.
// Per-step worker: gates = xproj + Whh^T.h (k-split 8 groups, overlaps
// leader's attention phase) + alpha.G (from LDS), col-sliced, no cross-block
// reduction.
// ---------------------------------------------------------------------------
__global__ __launch_bounds__(256, 1)
void persist_kernel(float* __restrict__ gbuf,           // [32][2048]
                    float* __restrict__ hF,             // [32][512]
                    ushort_t* __restrict__ hseqB,       // [21][32][512]
                    const ushort_t* __restrict__ encPB, // [6272][512]
                    const ushort_t* __restrict__ decWB, // [512][512]
                    const float* __restrict__ dec_b,
                    const float* __restrict__ full_W,
                    const float* __restrict__ full_b,
                    float* __restrict__ alpha,          // [32][200]
                    const ushort_t* __restrict__ GB,    // [6272][2048]
                    const ushort_t* __restrict__ WhhT,  // [512][2048]
                    const float* __restrict__ xproj,    // [640][2048]
                    unsigned* __restrict__ flags,       // [32][32]: w0=hflag, w1=aflag
                    unsigned* __restrict__ cntB)        // [32][32]
{
    __shared__ ushort_t Gs[196][256];   // 100,352 B: this block's G col-slice
    __shared__ float hsh[512];
    __shared__ float sred[8][32][8];    // 8 KB cross-group reduce scratch
    __shared__ float fws[512];
    __shared__ float dps[512];
    __shared__ float es[200];
    __shared__ float al[200];

    const int tid = threadIdx.x;
    const int b = blockIdx.x & 31;      // all 8 blocks of b -> same XCD
    const int s = blockIdx.x >> 5;
    const int jbase = s * 256;

    unsigned* fH  = &flags[b * 32 + 0];
    unsigned* fA  = &flags[b * 32 + 1];
    unsigned* cnt = &cntB[b * 32];

    // ---- one-time: stage this block's G slice into LDS (25.6 MB chip-wide)
    {
        const int r0 = tid >> 5, c = (tid & 31) * 8;
        for (int i = 0; i < 25; i++) {
            int r = i * 8 + r0;
            if (r < 196)
                *(u16x8*)&Gs[r][c] =
                    *(const u16x8*)&GB[((size_t)(b * P_ + r)) * 2048 + jbase + c];
        }
    }

    const int kg = tid >> 5, cg = tid & 31;   // 8 reduce-groups x 32 col-groups
    float* sredF = &sred[0][0][0];

    if (s == 0) {
        // ============================ LEADER (+ cols 0..255 worker) ============================
        float c0 = 0.f, c1 = 0.f;
        if (tid < 128)
            *(float4*)&fws[tid * 4] = *(const float4*)&full_W[tid * 4];

        for (int t = 0; t <= T_; t++) {
            if (t > 0) wait_ge(cnt, 7u * (unsigned)t);

            if (t == 0) {
#pragma unroll
                for (int it = 0; it < 2; it++) {
                    int u = tid + it * 256;
                    hsh[u] = 0.f;
                    hF[b * 512 + u] = 0.f;
                }
            } else {
#pragma unroll
                for (int it = 0; it < 2; it++) {
                    int u = tid + it * 256;
                    float gi = gbuf[b * 2048 + u];
                    float gf = gbuf[b * 2048 + 512 + u];
                    float gg = gbuf[b * 2048 + 1024 + u];
                    float go = gbuf[b * 2048 + 1536 + u];
                    float ig = 1.f / (1.f + expf(-gi));
                    float fg = 1.f / (1.f + expf(-gf));
                    float g_ = tanhf(gg);
                    float og = 1.f / (1.f + expf(-go));
                    float cold = it ? c1 : c0;
                    float cn = fg * cold + ig * g_;
                    float hn = og * tanhf(cn);
                    if (it) c1 = cn; else c0 = cn;
                    hsh[u] = hn;
                    hF[b * 512 + u] = hn;
                    hseqB[(size_t)t * 16384 + b * 512 + u] = bf_rne(hn);
                }
            }
            __syncthreads();
            if (tid == 0)
                __hip_atomic_store(fH, (unsigned)(t + 1),
                                   __ATOMIC_RELEASE, __HIP_MEMORY_SCOPE_AGENT);
            if (t == T_) break;

            const int lane = tid & 63, wave = tid >> 6;
            const int g16 = lane >> 4, gl = lane & 15;
            // dps = h . dec_W^T + dec_b
#pragma unroll 4
            for (int q = 0; q < 32; q++) {
                int a = wave * 128 + q * 4 + g16;
                const ushort_t* wr = decWB + (size_t)a * 512;
                float sacc = 0.f;
#pragma unroll
                for (int jj = 0; jj < 4; jj++) {
                    u16x8 wv = *(const u16x8*)&wr[jj * 128 + gl * 8];
                    float4 h0 = *(float4*)&hsh[jj * 128 + gl * 8];
                    float4 h1 = *(float4*)&hsh[jj * 128 + gl * 8 + 4];
                    sacc += b2f(wv[0]) * h0.x + b2f(wv[1]) * h0.y
                          + b2f(wv[2]) * h0.z + b2f(wv[3]) * h0.w
                          + b2f(wv[4]) * h1.x + b2f(wv[5]) * h1.y
                          + b2f(wv[6]) * h1.z + b2f(wv[7]) * h1.w;
                }
                sacc += __shfl_xor(sacc, 1, 64); sacc += __shfl_xor(sacc, 2, 64);
                sacc += __shfl_xor(sacc, 4, 64); sacc += __shfl_xor(sacc, 8, 64);
                if (gl == 0) dps[a] = sacc + dec_b[a];
            }
            __syncthreads();
            // energies
            const float fb0 = full_b[0];
            for (int i = 0; i < 13; i++) {
                int q = wave + 4 * i;
                if (q >= 49) break;
                int p = q * 4 + g16;
                const ushort_t* ep = encPB + ((size_t)(b * P_) + p) * 512;
                float sacc = 0.f;
#pragma unroll
                for (int jj = 0; jj < 4; jj++) {
                    u16x8 ev = *(const u16x8*)&ep[jj * 128 + gl * 8];
                    float4 d0 = *(float4*)&dps[jj * 128 + gl * 8];
                    float4 d1 = *(float4*)&dps[jj * 128 + gl * 8 + 4];
                    float4 f0 = *(float4*)&fws[jj * 128 + gl * 8];
                    float4 f1 = *(float4*)&fws[jj * 128 + gl * 8 + 4];
                    sacc += fmaxf(b2f(ev[0]) + d0.x, 0.f) * f0.x
                          + fmaxf(b2f(ev[1]) + d0.y, 0.f) * f0.y
                          + fmaxf(b2f(ev[2]) + d0.z, 0.f) * f0.z
                          + fmaxf(b2f(ev[3]) + d0.w, 0.f) * f0.w
                          + fmaxf(b2f(ev[4]) + d1.x, 0.f) * f1.x
                          + fmaxf(b2f(ev[5]) + d1.y, 0.f) * f1.y
                          + fmaxf(b2f(ev[6]) + d1.z, 0.f) * f1.z
                          + fmaxf(b2f(ev[7]) + d1.w, 0.f) * f1.w;
                }
                sacc += __shfl_xor(sacc, 1, 64); sacc += __shfl_xor(sacc, 2, 64);
                sacc += __shfl_xor(sacc, 4, 64); sacc += __shfl_xor(sacc, 8, 64);
                if (gl == 0) es[p] = sacc + fb0;
            }
            __syncthreads();
            // softmax (wave 0) -> alpha (global + LDS)
            if (tid < 64) {
                float v[4]; int pv[4]; int n = 0;
                for (int q = 0; q < 4; q++) {
                    int p = tid + 64 * q;
                    if (p < P_) { pv[n] = p; v[n] = es[p]; n++; }
                }
                float m = -1e30f;
                for (int q = 0; q < n; q++) m = fmaxf(m, v[q]);
#pragma unroll
                for (int off = 32; off > 0; off >>= 1) m = fmaxf(m, __shfl_xor(m, off, 64));
                float ssum = 0.f;
                for (int q = 0; q < n; q++) { v[q] = expf(v[q] - m); ssum += v[q]; }
#pragma unroll
                for (int off = 32; off > 0; off >>= 1) ssum += __shfl_xor(ssum, off, 64);
                float rinv = 1.f / ssum;
                for (int q = 0; q < n; q++) {
                    float a_ = v[q] * rinv;
                    alpha[b * 200 + pv[q]] = a_;
                    al[pv[q]] = a_;
                }
            }
            __syncthreads();
            if (tid == 0)
                __hip_atomic_store(fA, (unsigned)(t + 1),
                                   __ATOMIC_RELEASE, __HIP_MEMORY_SCOPE_AGENT);

            // ---- own worker part (cols 0..255): Whh^T.h slice
            {
                float wa[8] = {0.f,0.f,0.f,0.f,0.f,0.f,0.f,0.f};
                const ushort_t* wp = WhhT + (size_t)(kg * 64) * 2048 + jbase + cg * 8;
#pragma unroll 8
                for (int kk = 0; kk < 64; kk++) {
                    u16x8 wv = *(const u16x8*)&wp[(size_t)kk * 2048];
                    float hv = hsh[kg * 64 + kk];
#pragma unroll
                    for (int q = 0; q < 8; q++) wa[q] += b2f(wv[q]) * hv;
                }
#pragma unroll
                for (int q = 0; q < 8; q++) sred[kg][cg][q] = wa[q];
            }
            __syncthreads();
            float g = xproj[(size_t)(t * 32 + b) * 2048 + jbase + tid];
#pragma unroll
            for (int k2 = 0; k2 < 8; k2++) g += sredF[k2 * 256 + tid];
            __syncthreads();
            // ---- alpha.G slice from LDS
            {
                int p0 = (kg < 4) ? kg * 25 : 100 + (kg - 4) * 24;
                int np = (kg < 4) ? 25 : 24;
                float pa[8] = {0.f,0.f,0.f,0.f,0.f,0.f,0.f,0.f};
#pragma unroll 4
                for (int i = 0; i < np; i++) {
                    int p = p0 + i;
                    float av = al[p];
                    u16x8 gv = *(const u16x8*)&Gs[p][cg * 8];
#pragma unroll
                    for (int q = 0; q < 8; q++) pa[q] += b2f(gv[q]) * av;
                }
#pragma unroll
                for (int q = 0; q < 8; q++) sred[kg][cg][q] = pa[q];
            }
            __syncthreads();
#pragma unroll
            for (int k2 = 0; k2 < 8; k2++) g += sredF[k2 * 256 + tid];
            gbuf[(size_t)b * 2048 + jbase + tid] = g;
            // no cnt increment for s=0: leader proceeds once the 7 others post
        }
    } else {
        // ============================ WORKER (cols s*256 .. +255) ============================
        for (int t = 0; t < T_; t++) {
            wait_ge(fH, (unsigned)(t + 1));
            *(float2*)&hsh[tid * 2] = *(const float2*)&hF[b * 512 + tid * 2];
            __syncthreads();

            // Whh^T.h slice (overlaps leader's attention phase)
            {
                float wa[8] = {0.f,0.f,0.f,0.f,0.f,0.f,0.f,0.f};
                const ushort_t* wp = WhhT + (size_t)(kg * 64) * 2048 + jbase + cg * 8;
#pragma unroll 8
                for (int kk = 0; kk < 64; kk++) {
                    u16x8 wv = *(const u16x8*)&wp[(size_t)kk * 2048];
                    float hv = hsh[kg * 64 + kk];
#pragma unroll
                    for (int q = 0; q < 8; q++) wa[q] += b2f(wv[q]) * hv;
                }
#pragma unroll
                for (int q = 0; q < 8; q++) sred[kg][cg][q] = wa[q];
            }
            __syncthreads();
            float g = xproj[(size_t)(t * 32 + b) * 2048 + jbase + tid];
#pragma unroll
            for (int k2 = 0; k2 < 8; k2++) g += sredF[k2 * 256 + tid];

            wait_ge(fA, (unsigned)(t + 1));   // internal barrier guards sred reuse
            if (tid < P_) al[tid] = alpha[b * 200 + tid];
            __syncthreads();

            // alpha.G slice from LDS (was the 25.6 MB/step HBM stream)
            {
                int p0 = (kg < 4) ? kg * 25 : 100 + (kg - 4) * 24;
                int np = (kg < 4) ? 25 : 24;
                float pa[8] = {0.f,0.f,0.f,0.f,0.f,0.f,0.f,0.f};
#pragma unroll 4
                for (int i = 0; i < np; i++) {
                    int p = p0 + i;
                    float av = al[p];
                    u16x8 gv = *(const u16x8*)&Gs[p][cg * 8];
#pragma unroll
                    for (int q = 0; q < 8; q++) pa[q] += b2f(gv[q]) * av;
                }
#pragma unroll
                for (int q = 0; q < 8; q++) sred[kg][cg][q] = pa[q];
            }
            __syncthreads();
#pragma unroll
            for (int k2 = 0; k2 < 8; k2++) g += sredF[k2 * 256 + tid];
            gbuf[(size_t)b * 2048 + jbase + tid] = g;
            __syncthreads();
            if (tid == 0)
                __hip_atomic_fetch_add(cnt, 1u,
                                       __ATOMIC_RELEASE, __HIP_MEMORY_SCOPE_AGENT);
        }
    }
}

// ---------------------------------------------------------------------------
extern "C" void kernel_launch(void* const* d_in, const int* in_sizes, int n_in,
                              void* d_out, int out_size, void* d_ws, size_t ws_size,
                              hipStream_t stream)
{
    (void)in_sizes; (void)n_in; (void)out_size; (void)ws_size;
    const float* feat   = (const float*)d_in[0];
    const int*   caps   = (const int*)  d_in[1];
    const float* emb    = (const float*)d_in[2];
    const float* W_ih   = (const float*)d_in[3];
    const float* b_ih   = (const float*)d_in[4];
    const float* W_hh   = (const float*)d_in[5];
    const float* b_hh   = (const float*)d_in[6];
    const float* fc_W   = (const float*)d_in[7];
    const float* fc_b   = (const float*)d_in[8];
    const float* enc_W  = (const float*)d_in[9];
    const float* enc_b  = (const float*)d_in[10];
    const float* dec_W  = (const float*)d_in[11];
    const float* dec_b  = (const float*)d_in[12];
    const float* full_W = (const float*)d_in[13];
    const float* full_b = (const float*)d_in[14];
    float* out = (float*)d_out;

    // workspace carve (~90 MB), 128B-aligned chunks
    char* w = (char*)d_ws;
    ushort_t* featB = (ushort_t*)w;              w += 25690112;  // [6272][2048]
    ushort_t* encWB = (ushort_t*)w;              w += 2097152;   // [512][2048]
    ushort_t* fcWB  = (ushort_t*)w;              w += 10240000;  // [10000][512]
    ushort_t* decWB = (ushort_t*)w;              w += 524288;    // [512][512]
    ushort_t* WihCB = (ushort_t*)w;              w += 8388608;   // [2048][2048]
    ushort_t* WihEB = (ushort_t*)w;              w += 2097152;   // [2048][512]
    ushort_t* WhhT  = (ushort_t*)w;              w += 2097152;   // [512][2048]
    ushort_t* XB    = (ushort_t*)w;              w += 655360;    // [640][512]
    ushort_t* encPB = (ushort_t*)w;              w += 6422528;   // [6272][512]
    ushort_t* GB    = (ushort_t*)w;              w += 25690112;  // [6272][2048]
    float*    xproj = (float*)w;                 w += 5242880;   // [640][2048]
    float*    bsum  = (float*)w;                 w += 8192;      // [2048]
    float*    zbuf  = (float*)w;                 w += 8192;      // [2048]
    float*    hF    = (float*)w;                 w += 65536;     // [32][512]
    ushort_t* hseqB = (ushort_t*)w;              w += 688128;    // [21][32][512]
    float*    gbuf  = (float*)w;                 w += 262144;    // [32][2048]
    float*    alpha = (float*)w;                 w += 25600;     // [32][200]
    unsigned* flags = (unsigned*)w;              w += 4096;      // [32][32] hflag/aflag
    unsigned* cntB  = (unsigned*)w;              w += 4096;      // [32][32]

    // zero per-b sync flags (contiguous 8 KB; ws re-poisoned each replay)
    hipMemsetAsync(flags, 0, 8192, stream);

    // one-time converts / extracts / transposes / gathers (1 node)
    cvt_all_kernel<<<13125, 256, 0, stream>>>(
        feat, enc_W, fc_W, dec_W, W_ih, W_hh, emb, caps, b_ih, b_hh,
        featB, encWB, fcWB, decWB, WihCB, WihEB, WhhT, XB, bsum, zbuf);

    // enc_proj: [6272,2048]x[512,2048]^T -> encPB bf16
    mfma_gemm_kernel<<<dim3(49, 4), 256, 0, stream>>>(
        featB, encWB, enc_b, encPB, nullptr, 2048, 512, 0);

    // G = feat . W_ih[:,512:]^T : [6272,2048]x[2048,2048]^T -> GB bf16
    mfma_gemm_kernel<<<dim3(49, 16), 256, 0, stream>>>(
        featB, WihCB, zbuf, GB, nullptr, 2048, 2048, 0);

    // xproj = X . W_ih[:,:512]^T + (b_ih+b_hh): [640,512]x[2048,512]^T -> f32
    mfma_gemm_kernel<<<dim3(5, 16), 256, 0, stream>>>(
        XB, WihEB, bsum, nullptr, xproj, 512, 2048, 2);

    // persistent 20-step recurrent loop: 256 blocks, G resident in LDS
    persist_kernel<<<NBLK, 256, 0, stream>>>(
        gbuf, hF, hseqB, encPB, decWB, dec_b, full_W, full_b,
        alpha, GB, WhhT, xproj, flags, cntB);

    // batched vocab FC: [640,512]x[10000,512]^T -> out (f32, remapped rows)
    mfma_gemm_kernel<<<dim3(5, 79), 256, 0, stream>>>(
        hseqB + 16384, fcWB, fc_b, nullptr, out, 512, V_, 1);
}

// Round 2
// 1028.223 us; speedup vs baseline: 2.0426x; 1.0709x over previous
//
#include <hip/hip_runtime.h>
#include <math.h>

#define B_   32
#define P_   196
#define F_   2048
#define E_   512
#define H_   512
#define V_   10000
#define T_   20
#define GSZ  8            // blocks per batch-element group (all peers now)
#define NBLK (B_ * GSZ)   // 256 persistent blocks = 1 per CU (LDS-limited)

typedef unsigned short ushort_t;
typedef ushort_t u16x8 __attribute__((ext_vector_type(8)));
typedef ushort_t u16x2 __attribute__((ext_vector_type(2)));
typedef short    bf16x8 __attribute__((ext_vector_type(8)));
typedef float    f32x4  __attribute__((ext_vector_type(4)));

__device__ __forceinline__ ushort_t bf_rne(float x) {
    union { float f; unsigned u; } v; v.f = x;
    unsigned r = v.u + 0x7FFFu + ((v.u >> 16) & 1u);
    return (ushort_t)(r >> 16);
}
__device__ __forceinline__ float b2f(ushort_t u) {
    union { unsigned u; float f; } v; v.u = ((unsigned)u) << 16;
    return v.f;
}

// Column permutation: g-col j -> P(j) = s_own*256 + ri*32 + gi*8 + e.
// chunk=j>>3 (8-col chunk), gi=chunk>>6 (gate), r=chunk&63 (pos in gate),
// s_own=r&7 (owner block), ri=r>>3, e=j&7. Gate stride 512 = 64 chunks, so
// the 4 gates of one hidden unit all map to the same owner -> local pointwise.
__device__ __forceinline__ int permc(int chunk) {   // chunk in [0,256) -> new chunk
    int gi = chunk >> 6, r = chunk & 63;
    return (r & 7) * 32 + (r >> 3) * 4 + gi;
}

// ---------------------------------------------------------------------------
// One-time conversion mega-kernel (1 node): bf16 converts / extracts /
// transposes / caption-gather / g-col permutations. 13125 blocks x 256 thr.
// ---------------------------------------------------------------------------
__global__ __launch_bounds__(256)
void cvt_all_kernel(const float* __restrict__ feat, const float* __restrict__ enc_W,
                    const float* __restrict__ fc_W, const float* __restrict__ dec_W,
                    const float* __restrict__ W_ih, const float* __restrict__ W_hh,
                    const float* __restrict__ emb, const int* __restrict__ captions,
                    const float* __restrict__ b_ih, const float* __restrict__ b_hh,
                    ushort_t* __restrict__ featB, ushort_t* __restrict__ encWB,
                    ushort_t* __restrict__ fcWB, ushort_t* __restrict__ decWB,
                    ushort_t* __restrict__ WihCB, ushort_t* __restrict__ WihEB,
                    ushort_t* __restrict__ WhhT, ushort_t* __restrict__ XB,
                    float* __restrict__ bsum, float* __restrict__ zbuf)
{
    const int blk = blockIdx.x, tid = threadIdx.x;
    if (blk < 6272) {                       // featB flat
        size_t i = (size_t)blk * 2048 + tid * 8;
        float4 a = *(const float4*)&feat[i], b = *(const float4*)&feat[i + 4];
        u16x8 o; o[0]=bf_rne(a.x); o[1]=bf_rne(a.y); o[2]=bf_rne(a.z); o[3]=bf_rne(a.w);
        o[4]=bf_rne(b.x); o[5]=bf_rne(b.y); o[6]=bf_rne(b.z); o[7]=bf_rne(b.w);
        *(u16x8*)&featB[i] = o;
    } else if (blk < 6784) {                // encWB
        size_t i = (size_t)(blk - 6272) * 2048 + tid * 8;
        float4 a = *(const float4*)&enc_W[i], b = *(const float4*)&enc_W[i + 4];
        u16x8 o; o[0]=bf_rne(a.x); o[1]=bf_rne(a.y); o[2]=bf_rne(a.z); o[3]=bf_rne(a.w);
        o[4]=bf_rne(b.x); o[5]=bf_rne(b.y); o[6]=bf_rne(b.z); o[7]=bf_rne(b.w);
        *(u16x8*)&encWB[i] = o;
    } else if (blk < 9284) {                // fcWB
        size_t i = (size_t)(blk - 6784) * 2048 + tid * 8;
        float4 a = *(const float4*)&fc_W[i], b = *(const float4*)&fc_W[i + 4];
        u16x8 o; o[0]=bf_rne(a.x); o[1]=bf_rne(a.y); o[2]=bf_rne(a.z); o[3]=bf_rne(a.w);
        o[4]=bf_rne(b.x); o[5]=bf_rne(b.y); o[6]=bf_rne(b.z); o[7]=bf_rne(b.w);
        *(u16x8*)&fcWB[i] = o;
    } else if (blk < 9412) {                // decWB
        size_t i = (size_t)(blk - 9284) * 2048 + tid * 8;
        float4 a = *(const float4*)&dec_W[i], b = *(const float4*)&dec_W[i + 4];
        u16x8 o; o[0]=bf_rne(a.x); o[1]=bf_rne(a.y); o[2]=bf_rne(a.z); o[3]=bf_rne(a.w);
        o[4]=bf_rne(b.x); o[5]=bf_rne(b.y); o[6]=bf_rne(b.z); o[7]=bf_rne(b.w);
        *(u16x8*)&decWB[i] = o;
    } else if (blk < 11460) {               // WihCB[P(j)] = bf16(W_ih[j, 512:2560])
        int j = blk - 9412, f = tid * 8;
        int Pj = permc(j >> 3) * 8 + (j & 7);
        const float* s = &W_ih[(size_t)j * 2560 + 512 + f];
        float4 a = *(const float4*)&s[0], b = *(const float4*)&s[4];
        u16x8 o; o[0]=bf_rne(a.x); o[1]=bf_rne(a.y); o[2]=bf_rne(a.z); o[3]=bf_rne(a.w);
        o[4]=bf_rne(b.x); o[5]=bf_rne(b.y); o[6]=bf_rne(b.z); o[7]=bf_rne(b.w);
        *(u16x8*)&WihCB[(size_t)Pj * 2048 + f] = o;
    } else if (blk < 11972) {               // WihEB[P(j)] = bf16(W_ih[j, 0:512])
        size_t idx = (size_t)(blk - 11460) * 2048 + tid * 8;
        int j = (int)(idx >> 9), f = (int)(idx & 511);
        int Pj = permc(j >> 3) * 8 + (j & 7);
        const float* s = &W_ih[(size_t)j * 2560 + f];
        float4 a = *(const float4*)&s[0], b = *(const float4*)&s[4];
        u16x8 o; o[0]=bf_rne(a.x); o[1]=bf_rne(a.y); o[2]=bf_rne(a.z); o[3]=bf_rne(a.w);
        o[4]=bf_rne(b.x); o[5]=bf_rne(b.y); o[6]=bf_rne(b.z); o[7]=bf_rne(b.w);
        *(u16x8*)&WihEB[(size_t)Pj * 512 + f] = o;
    } else if (blk < 12484) {               // WhhT[k][P(j)] = bf16(W_hh[j][k])
        int k = blk - 11972, j0 = tid * 8;
        int nc = permc(tid);                // all 8 j's are one chunk (chunk = tid)
        u16x8 o;
#pragma unroll
        for (int q = 0; q < 8; q++) o[q] = bf_rne(W_hh[(size_t)(j0 + q) * 512 + k]);
        *(u16x8*)&WhhT[(size_t)k * 2048 + nc * 8] = o;
    } else if (blk < 13124) {               // XB[m] = bf16(emb[captions]), m = t*32+b
        int m = blk - 12484;
        int tt = m >> 5, b = m & 31;
        int cap = captions[b * T_ + tt];
        int i = tid * 2;
        u16x2 o;
        o[0] = bf_rne(emb[(size_t)cap * 512 + i]);
        o[1] = bf_rne(emb[(size_t)cap * 512 + i + 1]);
        *(u16x2*)&XB[(size_t)m * 512 + i] = o;
    } else {                                // bsum (permuted) + zbuf
        int nc = permc(tid);
        int j0 = tid * 8;
#pragma unroll
        for (int q = 0; q < 8; q++) {
            bsum[nc * 8 + q] = b_ih[j0 + q] + b_hh[j0 + q];
            zbuf[j0 + q] = 0.f;
        }
    }
}

// ---------------------------------------------------------------------------
// bf16 MFMA GEMM: C[m,n] = A[m,:].B[n,:] + bias[n], A/B bf16 K-major.
// 128x128 tile, 4 waves, 4x4 of 16x16x32 MFMA per wave.
// mode 0: bf16 store.  mode 1: f32 store, crow=(m&31)*20+(m>>5), guard n<N.
// mode 2: f32 store plain.
// ---------------------------------------------------------------------------
__global__ __launch_bounds__(256)
void mfma_gemm_kernel(const ushort_t* __restrict__ A, const ushort_t* __restrict__ B,
                      const float* __restrict__ bias, ushort_t* __restrict__ Cb,
                      float* __restrict__ Cf, int K, int N, int mode)
{
    __shared__ ushort_t As[128][32];
    __shared__ ushort_t Bs[128][32];
    const int tid = threadIdx.x;
    const int m0 = blockIdx.x * 128, n0 = blockIdx.y * 128;
    const int wave = tid >> 6, lane = tid & 63;
    const int wm = (wave & 1) * 64, wn = (wave >> 1) * 64;
    const int lm = lane & 15, lk = (lane >> 4) * 8;

    f32x4 acc[4][4];
#pragma unroll
    for (int mt = 0; mt < 4; mt++)
#pragma unroll
        for (int nt = 0; nt < 4; nt++)
#pragma unroll
            for (int r = 0; r < 4; r++) acc[mt][nt][r] = 0.f;

    for (int k0 = 0; k0 < K; k0 += 32) {
#pragma unroll
        for (int i = 0; i < 2; i++) {
            int gi  = tid + i * 256;
            int row = gi >> 2;
            int gr  = (gi & 3) * 8;
            *(u16x8*)&As[row][gr] = *(const u16x8*)&A[(size_t)(m0 + row) * K + k0 + gr];
            int brow = n0 + row; if (brow >= N) brow = N - 1;
            *(u16x8*)&Bs[row][gr] = *(const u16x8*)&B[(size_t)brow * K + k0 + gr];
        }
        __syncthreads();
        bf16x8 af[4], bv[4];
#pragma unroll
        for (int mt = 0; mt < 4; mt++)
            af[mt] = *(const bf16x8*)&As[wm + mt * 16 + lm][lk];
#pragma unroll
        for (int nt = 0; nt < 4; nt++)
            bv[nt] = *(const bf16x8*)&Bs[wn + nt * 16 + lm][lk];
#pragma unroll
        for (int mt = 0; mt < 4; mt++)
#pragma unroll
            for (int nt = 0; nt < 4; nt++)
                acc[mt][nt] = __builtin_amdgcn_mfma_f32_16x16x32_bf16(
                    af[mt], bv[nt], acc[mt][nt], 0, 0, 0);
        __syncthreads();
    }

    const int rb = (lane >> 4) * 4;
#pragma unroll
    for (int nt = 0; nt < 4; nt++) {
        int n = n0 + wn + nt * 16 + lm;
        int nc = n < N ? n : N - 1;
        float bz = bias[nc];
#pragma unroll
        for (int mt = 0; mt < 4; mt++) {
            int mbase = m0 + wm + mt * 16 + rb;
#pragma unroll
            for (int r = 0; r < 4; r++) {
                float v = acc[mt][nt][r] + bz;
                int m = mbase + r;
                if (mode == 0) {
                    Cb[(size_t)m * N + n] = bf_rne(v);
                } else if (n < N) {
                    int crow = (mode == 1) ? ((m & 31) * 20 + (m >> 5)) : m;
                    Cf[(size_t)crow * N + n] = v;
                }
            }
        }
    }
}

// Relaxed-only poll: NO acquire -> no L2 invalidate, weights stay L2-hot.
// The only cross-block payload (h) is read via agent-scope relaxed atomic
// loads which bypass L1/L2 to the coherence point by ISA definition.
__device__ __forceinline__ void wait_cnt(unsigned* p, unsigned target) {
    if (threadIdx.x == 0) {
        while (__hip_atomic_load(p, __ATOMIC_RELAXED, __HIP_MEMORY_SCOPE_AGENT) < target)
            __builtin_amdgcn_s_sleep(1);
    }
    __syncthreads();
}

// ---------------------------------------------------------------------------
// Persistent 20-step decoder, ONE sync hop per step, zero acquires.
// 256 blocks = 32 groups x 8. Block (b,s) owns 256 permuted g-cols
// [s*256, s*256+256) = complete i/f/g/o gate quadruples for 64 hidden units
// -> pointwise LSTM is block-local (c in regs). G slice lives in LDS (100 KB,
// staged once). Attention (dec_proj+energies+softmax) computed redundantly
// per block from L2-resident decWB/encPB. Per step: poll hcnt>=8t (relaxed),
// read h via agent atomic loads, attention, Whh.h, alpha.G, pointwise,
// publish 64 h values via agent atomic stores, release-increment hcnt.
// hF double-buffered (step t reads buf[t&1], writes buf[(t+1)&1]).
// ---------------------------------------------------------------------------
__global__ __launch_bounds__(256, 1)
void persist_kernel(float* __restrict__ hbuf,           // [2][32][512]
                    ushort_t* __restrict__ hseqB,       // [21][32][512]
                    const ushort_t* __restrict__ encPB, // [6272][512]
                    const ushort_t* __restrict__ decWB, // [512][512]
                    const float* __restrict__ dec_b,
                    const float* __restrict__ full_W,
                    const float* __restrict__ full_b,
                    const ushort_t* __restrict__ GB,    // [6272][2048] col-permuted
                    const ushort_t* __restrict__ WhhT,  // [512][2048] col-permuted
                    const float* __restrict__ xproj,    // [640][2048] col-permuted
                    unsigned* __restrict__ hcnt)        // [32][32], use [b*32]
{
    __shared__ ushort_t Gs[196][256];   // 100,352 B: this block's G col-slice
    __shared__ float hsh[512];
    __shared__ float fws[512];
    __shared__ float dps[512];
    __shared__ float es[200];
    __shared__ float al[200];
    __shared__ float sred[8][32][9];    // padded: conflict-free reduce scratch
    __shared__ float gsh[256];

    const int tid = threadIdx.x;
    const int b = blockIdx.x & 31;      // all 8 blocks of b -> same XCD
    const int s = blockIdx.x >> 5;
    unsigned* cnt = &hcnt[b * 32];

    // ---- one-time: stage this block's (contiguous, permuted) G slice
    {
        const int r0 = tid >> 5, c = (tid & 31) * 8;
        for (int i = 0; i < 25; i++) {
            int r = i * 8 + r0;
            if (r < 196)
                *(u16x8*)&Gs[r][c] =
                    *(const u16x8*)&GB[((size_t)(b * P_ + r)) * 2048 + s * 256 + c];
        }
    }
    if (tid < 128)
        *(float4*)&fws[tid * 4] = *(const float4*)&full_W[tid * 4];

    const int lane = tid & 63, wave = tid >> 6;
    const int g16 = lane >> 4, gl = lane & 15;
    const int kg = tid >> 5, cg = tid & 31;
    const float fb0 = full_b[0];
    float c_reg = 0.f;

    for (int t = 0; t < T_; t++) {
        // ---- acquire h(t): one relaxed poll + agent atomic payload loads
        if (t == 0) {
            hsh[tid * 2] = 0.f; hsh[tid * 2 + 1] = 0.f;
        } else {
            wait_cnt(cnt, 8u * (unsigned)t);
            const float* hb = hbuf + ((size_t)(t & 1) * 32 + b) * 512;
            hsh[tid * 2] = __hip_atomic_load(&hb[tid * 2],
                                             __ATOMIC_RELAXED, __HIP_MEMORY_SCOPE_AGENT);
            hsh[tid * 2 + 1] = __hip_atomic_load(&hb[tid * 2 + 1],
                                             __ATOMIC_RELAXED, __HIP_MEMORY_SCOPE_AGENT);
        }
        __syncthreads();

        // ---- dps = h . dec_W^T + dec_b   (redundant per block, decWB in L2)
        if (t == 0) {
            dps[tid] = dec_b[tid];
            dps[tid + 256] = dec_b[tid + 256];
        } else {
#pragma unroll 4
            for (int q = 0; q < 32; q++) {
                int a = wave * 128 + q * 4 + g16;
                const ushort_t* wr = decWB + (size_t)a * 512;
                float sacc = 0.f;
#pragma unroll
                for (int jj = 0; jj < 4; jj++) {
                    u16x8 wv = *(const u16x8*)&wr[jj * 128 + gl * 8];
                    float4 h0 = *(float4*)&hsh[jj * 128 + gl * 8];
                    float4 h1 = *(float4*)&hsh[jj * 128 + gl * 8 + 4];
                    sacc += b2f(wv[0]) * h0.x + b2f(wv[1]) * h0.y
                          + b2f(wv[2]) * h0.z + b2f(wv[3]) * h0.w
                          + b2f(wv[4]) * h1.x + b2f(wv[5]) * h1.y
                          + b2f(wv[6]) * h1.z + b2f(wv[7]) * h1.w;
                }
                sacc += __shfl_xor(sacc, 1, 64); sacc += __shfl_xor(sacc, 2, 64);
                sacc += __shfl_xor(sacc, 4, 64); sacc += __shfl_xor(sacc, 8, 64);
                if (gl == 0) dps[a] = sacc + dec_b[a];
            }
        }
        __syncthreads();

        // ---- energies (12 uniform iters + wave-0 tail, unrolled x2)
#pragma unroll 2
        for (int i = 0; i < 12; i++) {
            int q = wave + 4 * i;
            int p = q * 4 + g16;
            const ushort_t* ep = encPB + ((size_t)(b * P_) + p) * 512;
            float sacc = 0.f;
#pragma unroll
            for (int jj = 0; jj < 4; jj++) {
                u16x8 ev = *(const u16x8*)&ep[jj * 128 + gl * 8];
                float4 d0 = *(float4*)&dps[jj * 128 + gl * 8];
                float4 d1 = *(float4*)&dps[jj * 128 + gl * 8 + 4];
                float4 f0 = *(float4*)&fws[jj * 128 + gl * 8];
                float4 f1 = *(float4*)&fws[jj * 128 + gl * 8 + 4];
                sacc += fmaxf(b2f(ev[0]) + d0.x, 0.f) * f0.x
                      + fmaxf(b2f(ev[1]) + d0.y, 0.f) * f0.y
                      + fmaxf(b2f(ev[2]) + d0.z, 0.f) * f0.z
                      + fmaxf(b2f(ev[3]) + d0.w, 0.f) * f0.w
                      + fmaxf(b2f(ev[4]) + d1.x, 0.f) * f1.x
                      + fmaxf(b2f(ev[5]) + d1.y, 0.f) * f1.y
                      + fmaxf(b2f(ev[6]) + d1.z, 0.f) * f1.z
                      + fmaxf(b2f(ev[7]) + d1.w, 0.f) * f1.w;
            }
            sacc += __shfl_xor(sacc, 1, 64); sacc += __shfl_xor(sacc, 2, 64);
            sacc += __shfl_xor(sacc, 4, 64); sacc += __shfl_xor(sacc, 8, 64);
            if (gl == 0) es[p] = sacc + fb0;
        }
        if (wave == 0) {                 // tail: q = 48, p = 192..195
            int p = 192 + g16;
            const ushort_t* ep = encPB + ((size_t)(b * P_) + p) * 512;
            float sacc = 0.f;
#pragma unroll
            for (int jj = 0; jj < 4; jj++) {
                u16x8 ev = *(const u16x8*)&ep[jj * 128 + gl * 8];
                float4 d0 = *(float4*)&dps[jj * 128 + gl * 8];
                float4 d1 = *(float4*)&dps[jj * 128 + gl * 8 + 4];
                float4 f0 = *(float4*)&fws[jj * 128 + gl * 8];
                float4 f1 = *(float4*)&fws[jj * 128 + gl * 8 + 4];
                sacc += fmaxf(b2f(ev[0]) + d0.x, 0.f) * f0.x
                      + fmaxf(b2f(ev[1]) + d0.y, 0.f) * f0.y
                      + fmaxf(b2f(ev[2]) + d0.z, 0.f) * f0.z
                      + fmaxf(b2f(ev[3]) + d0.w, 0.f) * f0.w
                      + fmaxf(b2f(ev[4]) + d1.x, 0.f) * f1.x
                      + fmaxf(b2f(ev[5]) + d1.y, 0.f) * f1.y
                      + fmaxf(b2f(ev[6]) + d1.z, 0.f) * f1.z
                      + fmaxf(b2f(ev[7]) + d1.w, 0.f) * f1.w;
            }
            sacc += __shfl_xor(sacc, 1, 64); sacc += __shfl_xor(sacc, 2, 64);
            sacc += __shfl_xor(sacc, 4, 64); sacc += __shfl_xor(sacc, 8, 64);
            if (gl == 0) es[p] = sacc + fb0;
        }
        __syncthreads();

        // ---- softmax (wave 0) -> al (LDS only; no global round-trip)
        if (tid < 64) {
            float v[4]; int pv[4]; int n = 0;
            for (int q = 0; q < 4; q++) {
                int p = tid + 64 * q;
                if (p < P_) { pv[n] = p; v[n] = es[p]; n++; }
            }
            float m = -1e30f;
            for (int q = 0; q < n; q++) m = fmaxf(m, v[q]);
#pragma unroll
            for (int off = 32; off > 0; off >>= 1) m = fmaxf(m, __shfl_xor(m, off, 64));
            float ssum = 0.f;
            for (int q = 0; q < n; q++) { v[q] = expf(v[q] - m); ssum += v[q]; }
#pragma unroll
            for (int off = 32; off > 0; off >>= 1) ssum += __shfl_xor(ssum, off, 64);
            float rinv = 1.f / ssum;
            for (int q = 0; q < n; q++) al[pv[q]] = v[q] * rinv;
        }
        __syncthreads();

        // ---- Whh^T.h slice (owned 256 cols, contiguous after permutation)
        {
            float wa[8] = {0.f,0.f,0.f,0.f,0.f,0.f,0.f,0.f};
            const ushort_t* wp = WhhT + (size_t)(kg * 64) * 2048 + s * 256 + cg * 8;
#pragma unroll 8
            for (int kk = 0; kk < 64; kk++) {
                u16x8 wv = *(const u16x8*)&wp[(size_t)kk * 2048];
                float hv = hsh[kg * 64 + kk];
#pragma unroll
                for (int q = 0; q < 8; q++) wa[q] += b2f(wv[q]) * hv;
            }
#pragma unroll
            for (int q = 0; q < 8; q++) sred[kg][cg][q] = wa[q];
        }
        __syncthreads();
        float g = xproj[(size_t)(t * 32 + b) * 2048 + s * 256 + tid];
#pragma unroll
        for (int k2 = 0; k2 < 8; k2++) g += sred[k2][tid >> 3][tid & 7];
        __syncthreads();

        // ---- alpha.G slice (from LDS)
        {
            int p0 = (kg < 4) ? kg * 25 : 100 + (kg - 4) * 24;
            int np = (kg < 4) ? 25 : 24;
            float pa[8] = {0.f,0.f,0.f,0.f,0.f,0.f,0.f,0.f};
#pragma unroll 4
            for (int i = 0; i < np; i++) {
                int p = p0 + i;
                float av = al[p];
                u16x8 gv = *(const u16x8*)&Gs[p][cg * 8];
#pragma unroll
                for (int q = 0; q < 8; q++) pa[q] += b2f(gv[q]) * av;
            }
#pragma unroll
            for (int q = 0; q < 8; q++) sred[kg][cg][q] = pa[q];
        }
        __syncthreads();
#pragma unroll
        for (int k2 = 0; k2 < 8; k2++) g += sred[k2][tid >> 3][tid & 7];
        gsh[tid] = g;
        __syncthreads();

        // ---- block-local pointwise LSTM for this block's 64 hidden units
        if (tid < 64) {
            int ri = tid >> 3, e = tid & 7;
            float gi = gsh[ri * 32 + e];
            float gf = gsh[ri * 32 + 8 + e];
            float gg = gsh[ri * 32 + 16 + e];
            float go = gsh[ri * 32 + 24 + e];
            float ig = 1.f / (1.f + expf(-gi));
            float fg = 1.f / (1.f + expf(-gf));
            float g_ = tanhf(gg);
            float og = 1.f / (1.f + expf(-go));
            c_reg = fg * c_reg + ig * g_;
            float hn = og * tanhf(c_reg);
            int u = 8 * s + 64 * ri + e;
            float* ho = hbuf + ((size_t)((t + 1) & 1) * 32 + b) * 512 + u;
            __hip_atomic_store(ho, hn, __ATOMIC_RELAXED, __HIP_MEMORY_SCOPE_AGENT);
            hseqB[(size_t)(t + 1) * 16384 + b * 512 + u] = bf_rne(hn);
        }
        __syncthreads();
        if (tid == 0)
            __hip_atomic_fetch_add(cnt, 1u,
                                   __ATOMIC_RELEASE, __HIP_MEMORY_SCOPE_AGENT);
    }
}

// ---------------------------------------------------------------------------
extern "C" void kernel_launch(void* const* d_in, const int* in_sizes, int n_in,
                              void* d_out, int out_size, void* d_ws, size_t ws_size,
                              hipStream_t stream)
{
    (void)in_sizes; (void)n_in; (void)out_size; (void)ws_size;
    const float* feat   = (const float*)d_in[0];
    const int*   caps   = (const int*)  d_in[1];
    const float* emb    = (const float*)d_in[2];
    const float* W_ih   = (const float*)d_in[3];
    const float* b_ih   = (const float*)d_in[4];
    const float* W_hh   = (const float*)d_in[5];
    const float* b_hh   = (const float*)d_in[6];
    const float* fc_W   = (const float*)d_in[7];
    const float* fc_b   = (const float*)d_in[8];
    const float* enc_W  = (const float*)d_in[9];
    const float* enc_b  = (const float*)d_in[10];
    const float* dec_W  = (const float*)d_in[11];
    const float* dec_b  = (const float*)d_in[12];
    const float* full_W = (const float*)d_in[13];
    const float* full_b = (const float*)d_in[14];
    float* out = (float*)d_out;

    // workspace carve (~90 MB), 128B-aligned chunks
    char* w = (char*)d_ws;
    ushort_t* featB = (ushort_t*)w;              w += 25690112;  // [6272][2048]
    ushort_t* encWB = (ushort_t*)w;              w += 2097152;   // [512][2048]
    ushort_t* fcWB  = (ushort_t*)w;              w += 10240000;  // [10000][512]
    ushort_t* decWB = (ushort_t*)w;              w += 524288;    // [512][512]
    ushort_t* WihCB = (ushort_t*)w;              w += 8388608;   // [2048][2048] (rows permuted)
    ushort_t* WihEB = (ushort_t*)w;              w += 2097152;   // [2048][512]  (rows permuted)
    ushort_t* WhhT  = (ushort_t*)w;              w += 2097152;   // [512][2048]  (cols permuted)
    ushort_t* XB    = (ushort_t*)w;              w += 655360;    // [640][512]
    ushort_t* encPB = (ushort_t*)w;              w += 6422528;   // [6272][512]
    ushort_t* GB    = (ushort_t*)w;              w += 25690112;  // [6272][2048] (cols permuted)
    float*    xproj = (float*)w;                 w += 5242880;   // [640][2048]  (cols permuted)
    float*    bsum  = (float*)w;                 w += 8192;      // [2048] (permuted)
    float*    zbuf  = (float*)w;                 w += 8192;      // [2048]
    float*    hbuf  = (float*)w;                 w += 131072;    // [2][32][512]
    ushort_t* hseqB = (ushort_t*)w;              w += 688128;    // [21][32][512]
    unsigned* hcnt  = (unsigned*)w;              w += 4096;      // [32][32]

    // zero per-b sync counters (ws re-poisoned each replay)
    hipMemsetAsync(hcnt, 0, 4096, stream);

    // one-time converts / extracts / transposes / gathers / permutes (1 node)
    cvt_all_kernel<<<13125, 256, 0, stream>>>(
        feat, enc_W, fc_W, dec_W, W_ih, W_hh, emb, caps, b_ih, b_hh,
        featB, encWB, fcWB, decWB, WihCB, WihEB, WhhT, XB, bsum, zbuf);

    // enc_proj: [6272,2048]x[512,2048]^T -> encPB bf16
    mfma_gemm_kernel<<<dim3(49, 4), 256, 0, stream>>>(
        featB, encWB, enc_b, encPB, nullptr, 2048, 512, 0);

    // G = feat . W_ihC^T (rows of WihCB permuted -> GB cols permuted) bf16
    mfma_gemm_kernel<<<dim3(49, 16), 256, 0, stream>>>(
        featB, WihCB, zbuf, GB, nullptr, 2048, 2048, 0);

    // xproj = X . W_ihE^T + bsum (cols permuted to match)
    mfma_gemm_kernel<<<dim3(5, 16), 256, 0, stream>>>(
        XB, WihEB, bsum, nullptr, xproj, 512, 2048, 2);

    // persistent 20-step recurrent loop: 1 hop/step, zero acquires
    persist_kernel<<<NBLK, 256, 0, stream>>>(
        hbuf, hseqB, encPB, decWB, dec_b, full_W, full_b,
        GB, WhhT, xproj, hcnt);

    // batched vocab FC: [640,512]x[10000,512]^T -> out (f32, remapped rows)
    mfma_gemm_kernel<<<dim3(5, 79), 256, 0, stream>>>(
        hseqB + 16384, fcWB, fc_b, nullptr, out, 512, V_, 1);
}

// Round 3
// 841.009 us; speedup vs baseline: 2.4972x; 1.2226x over previous
//
#include <hip/hip_runtime.h>
#include <math.h>

#define B_   32
#define P_   196
#define F_   2048
#define E_   512
#define H_   512
#define V_   10000
#define T_   20
#define GSZ  8            // blocks per batch-element group
#define NBLK (B_ * GSZ)   // 256 persistent blocks = 1 per CU (LDS-limited)

typedef unsigned short ushort_t;
typedef ushort_t u16x8 __attribute__((ext_vector_type(8)));
typedef ushort_t u16x2 __attribute__((ext_vector_type(2)));
typedef short    bf16x8 __attribute__((ext_vector_type(8)));
typedef float    f32x4  __attribute__((ext_vector_type(4)));

__device__ __forceinline__ ushort_t bf_rne(float x) {
    union { float f; unsigned u; } v; v.f = x;
    unsigned r = v.u + 0x7FFFu + ((v.u >> 16) & 1u);
    return (ushort_t)(r >> 16);
}
__device__ __forceinline__ float b2f(ushort_t u) {
    union { unsigned u; float f; } v; v.u = ((unsigned)u) << 16;
    return v.f;
}

// Column permutation: g-col j -> P(j) = s_own*256 + ri*32 + gi*8 + e.
// chunk=j>>3, gi=chunk>>6 (gate), r=chunk&63, owner=r&7, ri=r>>3, e=j&7.
// Gate stride 512 = 64 chunks -> all 4 gates of one hidden unit share owner.
__device__ __forceinline__ int permc(int chunk) {   // chunk in [0,256) -> new chunk
    int gi = chunk >> 6, r = chunk & 63;
    return (r & 7) * 32 + (r >> 3) * 4 + gi;
}

// ---------------------------------------------------------------------------
// One-time conversion mega-kernel (1 node): bf16 converts / extracts /
// transposes / caption-gather / g-col permutations. 13125 blocks x 256 thr.
// ---------------------------------------------------------------------------
__global__ __launch_bounds__(256)
void cvt_all_kernel(const float* __restrict__ feat, const float* __restrict__ enc_W,
                    const float* __restrict__ fc_W, const float* __restrict__ dec_W,
                    const float* __restrict__ W_ih, const float* __restrict__ W_hh,
                    const float* __restrict__ emb, const int* __restrict__ captions,
                    const float* __restrict__ b_ih, const float* __restrict__ b_hh,
                    ushort_t* __restrict__ featB, ushort_t* __restrict__ encWB,
                    ushort_t* __restrict__ fcWB, ushort_t* __restrict__ decWB,
                    ushort_t* __restrict__ WihCB, ushort_t* __restrict__ WihEB,
                    ushort_t* __restrict__ WhhT, ushort_t* __restrict__ XB,
                    float* __restrict__ bsum, float* __restrict__ zbuf)
{
    const int blk = blockIdx.x, tid = threadIdx.x;
    if (blk < 6272) {                       // featB flat
        size_t i = (size_t)blk * 2048 + tid * 8;
        float4 a = *(const float4*)&feat[i], b = *(const float4*)&feat[i + 4];
        u16x8 o; o[0]=bf_rne(a.x); o[1]=bf_rne(a.y); o[2]=bf_rne(a.z); o[3]=bf_rne(a.w);
        o[4]=bf_rne(b.x); o[5]=bf_rne(b.y); o[6]=bf_rne(b.z); o[7]=bf_rne(b.w);
        *(u16x8*)&featB[i] = o;
    } else if (blk < 6784) {                // encWB
        size_t i = (size_t)(blk - 6272) * 2048 + tid * 8;
        float4 a = *(const float4*)&enc_W[i], b = *(const float4*)&enc_W[i + 4];
        u16x8 o; o[0]=bf_rne(a.x); o[1]=bf_rne(a.y); o[2]=bf_rne(a.z); o[3]=bf_rne(a.w);
        o[4]=bf_rne(b.x); o[5]=bf_rne(b.y); o[6]=bf_rne(b.z); o[7]=bf_rne(b.w);
        *(u16x8*)&encWB[i] = o;
    } else if (blk < 9284) {                // fcWB
        size_t i = (size_t)(blk - 6784) * 2048 + tid * 8;
        float4 a = *(const float4*)&fc_W[i], b = *(const float4*)&fc_W[i + 4];
        u16x8 o; o[0]=bf_rne(a.x); o[1]=bf_rne(a.y); o[2]=bf_rne(a.z); o[3]=bf_rne(a.w);
        o[4]=bf_rne(b.x); o[5]=bf_rne(b.y); o[6]=bf_rne(b.z); o[7]=bf_rne(b.w);
        *(u16x8*)&fcWB[i] = o;
    } else if (blk < 9412) {                // decWB
        size_t i = (size_t)(blk - 9284) * 2048 + tid * 8;
        float4 a = *(const float4*)&dec_W[i], b = *(const float4*)&dec_W[i + 4];
        u16x8 o; o[0]=bf_rne(a.x); o[1]=bf_rne(a.y); o[2]=bf_rne(a.z); o[3]=bf_rne(a.w);
        o[4]=bf_rne(b.x); o[5]=bf_rne(b.y); o[6]=bf_rne(b.z); o[7]=bf_rne(b.w);
        *(u16x8*)&decWB[i] = o;
    } else if (blk < 11460) {               // WihCB[P(j)] = bf16(W_ih[j, 512:2560])
        int j = blk - 9412, f = tid * 8;
        int Pj = permc(j >> 3) * 8 + (j & 7);
        const float* s = &W_ih[(size_t)j * 2560 + 512 + f];
        float4 a = *(const float4*)&s[0], b = *(const float4*)&s[4];
        u16x8 o; o[0]=bf_rne(a.x); o[1]=bf_rne(a.y); o[2]=bf_rne(a.z); o[3]=bf_rne(a.w);
        o[4]=bf_rne(b.x); o[5]=bf_rne(b.y); o[6]=bf_rne(b.z); o[7]=bf_rne(b.w);
        *(u16x8*)&WihCB[(size_t)Pj * 2048 + f] = o;
    } else if (blk < 11972) {               // WihEB[P(j)] = bf16(W_ih[j, 0:512])
        size_t idx = (size_t)(blk - 11460) * 2048 + tid * 8;
        int j = (int)(idx >> 9), f = (int)(idx & 511);
        int Pj = permc(j >> 3) * 8 + (j & 7);
        const float* s = &W_ih[(size_t)j * 2560 + f];
        float4 a = *(const float4*)&s[0], b = *(const float4*)&s[4];
        u16x8 o; o[0]=bf_rne(a.x); o[1]=bf_rne(a.y); o[2]=bf_rne(a.z); o[3]=bf_rne(a.w);
        o[4]=bf_rne(b.x); o[5]=bf_rne(b.y); o[6]=bf_rne(b.z); o[7]=bf_rne(b.w);
        *(u16x8*)&WihEB[(size_t)Pj * 512 + f] = o;
    } else if (blk < 12484) {               // WhhT[k][P(j)] = bf16(W_hh[j][k])
        int k = blk - 11972, j0 = tid * 8;
        int nc = permc(tid);
        u16x8 o;
#pragma unroll
        for (int q = 0; q < 8; q++) o[q] = bf_rne(W_hh[(size_t)(j0 + q) * 512 + k]);
        *(u16x8*)&WhhT[(size_t)k * 2048 + nc * 8] = o;
    } else if (blk < 13124) {               // XB[m] = bf16(emb[captions]), m = t*32+b
        int m = blk - 12484;
        int tt = m >> 5, b = m & 31;
        int cap = captions[b * T_ + tt];
        int i = tid * 2;
        u16x2 o;
        o[0] = bf_rne(emb[(size_t)cap * 512 + i]);
        o[1] = bf_rne(emb[(size_t)cap * 512 + i + 1]);
        *(u16x2*)&XB[(size_t)m * 512 + i] = o;
    } else {                                // bsum (permuted) + zbuf
        int nc = permc(tid);
        int j0 = tid * 8;
#pragma unroll
        for (int q = 0; q < 8; q++) {
            bsum[nc * 8 + q] = b_ih[j0 + q] + b_hh[j0 + q];
            zbuf[j0 + q] = 0.f;
        }
    }
}

// ---------------------------------------------------------------------------
// bf16 MFMA GEMM: C[m,n] = A[m,:].B[n,:] + bias, A/B bf16 K-major.
// 128x128 tile, 4 waves, 4x4 of 16x16x32 MFMA per wave.
// mode 0: bf16 store, bias[n].  mode 1: f32 store, crow=(m&31)*20+(m>>5).
// mode 2: f32 store plain.      mode 3: bf16 store, ROW bias[m].
// ---------------------------------------------------------------------------
__global__ __launch_bounds__(256)
void mfma_gemm_kernel(const ushort_t* __restrict__ A, const ushort_t* __restrict__ B,
                      const float* __restrict__ bias, ushort_t* __restrict__ Cb,
                      float* __restrict__ Cf, int K, int N, int mode)
{
    __shared__ ushort_t As[128][32];
    __shared__ ushort_t Bs[128][32];
    const int tid = threadIdx.x;
    const int m0 = blockIdx.x * 128, n0 = blockIdx.y * 128;
    const int wave = tid >> 6, lane = tid & 63;
    const int wm = (wave & 1) * 64, wn = (wave >> 1) * 64;
    const int lm = lane & 15, lk = (lane >> 4) * 8;

    f32x4 acc[4][4];
#pragma unroll
    for (int mt = 0; mt < 4; mt++)
#pragma unroll
        for (int nt = 0; nt < 4; nt++)
#pragma unroll
            for (int r = 0; r < 4; r++) acc[mt][nt][r] = 0.f;

    for (int k0 = 0; k0 < K; k0 += 32) {
#pragma unroll
        for (int i = 0; i < 2; i++) {
            int gi  = tid + i * 256;
            int row = gi >> 2;
            int gr  = (gi & 3) * 8;
            *(u16x8*)&As[row][gr] = *(const u16x8*)&A[(size_t)(m0 + row) * K + k0 + gr];
            int brow = n0 + row; if (brow >= N) brow = N - 1;
            *(u16x8*)&Bs[row][gr] = *(const u16x8*)&B[(size_t)brow * K + k0 + gr];
        }
        __syncthreads();
        bf16x8 af[4], bv[4];
#pragma unroll
        for (int mt = 0; mt < 4; mt++)
            af[mt] = *(const bf16x8*)&As[wm + mt * 16 + lm][lk];
#pragma unroll
        for (int nt = 0; nt < 4; nt++)
            bv[nt] = *(const bf16x8*)&Bs[wn + nt * 16 + lm][lk];
#pragma unroll
        for (int mt = 0; mt < 4; mt++)
#pragma unroll
            for (int nt = 0; nt < 4; nt++)
                acc[mt][nt] = __builtin_amdgcn_mfma_f32_16x16x32_bf16(
                    af[mt], bv[nt], acc[mt][nt], 0, 0, 0);
        __syncthreads();
    }

    const int rb = (lane >> 4) * 4;
#pragma unroll
    for (int nt = 0; nt < 4; nt++) {
        int n = n0 + wn + nt * 16 + lm;
        int nc = n < N ? n : N - 1;
        float bz = (mode == 3) ? 0.f : bias[nc];
#pragma unroll
        for (int mt = 0; mt < 4; mt++) {
            int mbase = m0 + wm + mt * 16 + rb;
#pragma unroll
            for (int r = 0; r < 4; r++) {
                int m = mbase + r;
                float v = acc[mt][nt][r] + ((mode == 3) ? bias[m] : bz);
                if (mode == 0 || mode == 3) {
                    Cb[(size_t)m * N + n] = bf_rne(v);
                } else if (n < N) {
                    int crow = (mode == 1) ? ((m & 31) * 20 + (m >> 5)) : m;
                    Cf[(size_t)crow * N + n] = v;
                }
            }
        }
    }
}

// Relaxed-only poll: NO acquire -> no L2 invalidate, weights stay L2-hot.
// Cross-block payloads are moved via agent-scope relaxed atomic load/store
// which bypass L1/L2 to the coherence point.
__device__ __forceinline__ void wait_cnt(unsigned* p, unsigned target) {
    if (threadIdx.x == 0) {
        while (__hip_atomic_load(p, __ATOMIC_RELAXED, __HIP_MEMORY_SCOPE_AGENT) < target)
            __builtin_amdgcn_s_sleep(1);
    }
    __syncthreads();
}

// ---------------------------------------------------------------------------
// Persistent 20-step decoder, TWO relaxed hops per step, zero acquires,
// NO redundant attention. 256 blocks = 32 groups x 8. Block (b,s):
//  - owns 256 permuted g-cols (gate quadruples for 64 hidden units):
//    Whh.h slice, alpha.G slice (G in LDS, staged once), local pointwise.
//  - owns attention a-slice [s*64, s*64+64): dps_a = h.decW[a]+dec_b[a],
//    partial energies ep_s[p] = sum_a relu(encPT[a][b,p]+dps_a)*fw[a]
//    (relu splits over a!), published via relaxed agent stores + ecnt.
//    Whh.h GEMV overlaps the energy round-trip; then each block reduces
//    the 8 partials, softmaxes (cheap, redundant), and finishes locally.
// Per-step L2 traffic/XCD drops ~30MB -> ~11MB; dec_proj/energies chains
// (the exposed-latency hot spots at 1 wave/SIMD) shrink 8x.
// ---------------------------------------------------------------------------
__global__ __launch_bounds__(256, 1)
void persist_kernel(float* __restrict__ hbuf,           // [2][32][512]
                    ushort_t* __restrict__ hseqB,       // [21][32][512]
                    const ushort_t* __restrict__ encPT, // [512][6272] a-major
                    const ushort_t* __restrict__ decWB, // [512][512]
                    const float* __restrict__ dec_b,
                    const float* __restrict__ full_W,
                    const float* __restrict__ full_b,
                    const ushort_t* __restrict__ GB,    // [6272][2048] col-permuted
                    const ushort_t* __restrict__ WhhT,  // [512][2048] col-permuted
                    const float* __restrict__ xproj,    // [640][2048] col-permuted
                    float* __restrict__ epartG,         // [32][8][200]
                    unsigned* __restrict__ hcnt,        // [32][32]
                    unsigned* __restrict__ ecnt)        // [32][32]
{
    __shared__ ushort_t Gs[196][256];   // 100,352 B: this block's G col-slice
    __shared__ float hsh[512];
    __shared__ float fws[512];
    __shared__ float dps64[64];
    __shared__ float es[200];
    __shared__ float al[200];
    __shared__ float sred[8][32][9];    // padded: conflict-free reduce scratch
    __shared__ float gsh[256];

    const int tid = threadIdx.x;
    const int b = blockIdx.x & 31;      // all 8 blocks of b -> same XCD
    const int s = blockIdx.x >> 5;
    unsigned* hcn = &hcnt[b * 32];
    unsigned* ecn = &ecnt[b * 32];
    float* epb = epartG + (size_t)b * 1600;

    // ---- one-time: stage this block's (contiguous, permuted) G slice
    {
        const int r0 = tid >> 5, c = (tid & 31) * 8;
        for (int i = 0; i < 25; i++) {
            int r = i * 8 + r0;
            if (r < 196)
                *(u16x8*)&Gs[r][c] =
                    *(const u16x8*)&GB[((size_t)(b * P_ + r)) * 2048 + s * 256 + c];
        }
    }
    if (tid < 128)
        *(float4*)&fws[tid * 4] = *(const float4*)&full_W[tid * 4];

    const int lane = tid & 63, wave = tid >> 6;
    const int g16 = lane >> 4, gl = lane & 15;
    const int kg = tid >> 5, cg = tid & 31;
    const float fb0 = full_b[0];
    float c_reg = 0.f;

    for (int t = 0; t < T_; t++) {
        // ---- acquire h(t)
        if (t == 0) {
            hsh[tid * 2] = 0.f; hsh[tid * 2 + 1] = 0.f;
        } else {
            wait_cnt(hcn, 8u * (unsigned)t);
            const float* hb = hbuf + ((size_t)(t & 1) * 32 + b) * 512;
            hsh[tid * 2] = __hip_atomic_load(&hb[tid * 2],
                                             __ATOMIC_RELAXED, __HIP_MEMORY_SCOPE_AGENT);
            hsh[tid * 2 + 1] = __hip_atomic_load(&hb[tid * 2 + 1],
                                             __ATOMIC_RELAXED, __HIP_MEMORY_SCOPE_AGENT);
        }
        __syncthreads();

        // ---- dps for own a-slice: a_glob = s*64 + a, a in [0,64)
        if (t == 0) {
            if (tid < 64) dps64[tid] = dec_b[s * 64 + tid];
        } else {
#pragma unroll
            for (int q = 0; q < 4; q++) {
                int a = wave * 16 + q * 4 + g16;        // [0,64)
                const ushort_t* wr = decWB + (size_t)(s * 64 + a) * 512;
                float sacc = 0.f;
#pragma unroll
                for (int jj = 0; jj < 4; jj++) {
                    u16x8 wv = *(const u16x8*)&wr[jj * 128 + gl * 8];
                    float4 h0 = *(float4*)&hsh[jj * 128 + gl * 8];
                    float4 h1 = *(float4*)&hsh[jj * 128 + gl * 8 + 4];
                    sacc += b2f(wv[0]) * h0.x + b2f(wv[1]) * h0.y
                          + b2f(wv[2]) * h0.z + b2f(wv[3]) * h0.w
                          + b2f(wv[4]) * h1.x + b2f(wv[5]) * h1.y
                          + b2f(wv[6]) * h1.z + b2f(wv[7]) * h1.w;
                }
                sacc += __shfl_xor(sacc, 1, 64); sacc += __shfl_xor(sacc, 2, 64);
                sacc += __shfl_xor(sacc, 4, 64); sacc += __shfl_xor(sacc, 8, 64);
                if (gl == 0) dps64[a] = sacc + dec_b[s * 64 + a];
            }
        }
        __syncthreads();

        // ---- partial energies over own 64 a's; thread p = tid < 196
        if (tid < 196) {
            const ushort_t* ep = encPT + (size_t)(s * 64) * 6272 + b * P_ + tid;
            float e = 0.f;
#pragma unroll 8
            for (int a = 0; a < 64; a++)
                e += fmaxf(b2f(ep[(size_t)a * 6272]) + dps64[a], 0.f) * fws[s * 64 + a];
            __hip_atomic_store(&epb[s * 200 + tid], e,
                               __ATOMIC_RELAXED, __HIP_MEMORY_SCOPE_AGENT);
        }
        __syncthreads();
        if (tid == 0)
            __hip_atomic_fetch_add(ecn, 1u,
                                   __ATOMIC_RELEASE, __HIP_MEMORY_SCOPE_AGENT);

        // ---- Whh^T.h slice (overlaps the energy round-trip of other blocks)
        {
            float wa[8] = {0.f,0.f,0.f,0.f,0.f,0.f,0.f,0.f};
            const ushort_t* wp = WhhT + (size_t)(kg * 64) * 2048 + s * 256 + cg * 8;
#pragma unroll 8
            for (int kk = 0; kk < 64; kk++) {
                u16x8 wv = *(const u16x8*)&wp[(size_t)kk * 2048];
                float hv = hsh[kg * 64 + kk];
#pragma unroll
                for (int q = 0; q < 8; q++) wa[q] += b2f(wv[q]) * hv;
            }
#pragma unroll
            for (int q = 0; q < 8; q++) sred[kg][cg][q] = wa[q];
        }
        __syncthreads();
        float g = xproj[(size_t)(t * 32 + b) * 2048 + s * 256 + tid];
#pragma unroll
        for (int k2 = 0; k2 < 8; k2++) g += sred[k2][tid >> 3][tid & 7];

        // ---- gather partial energies, reduce, softmax (redundant, cheap)
        wait_cnt(ecn, 8u * (unsigned)(t + 1));
        if (tid < 196) {
            float e = fb0;
#pragma unroll
            for (int s2 = 0; s2 < 8; s2++)
                e += __hip_atomic_load(&epb[s2 * 200 + tid],
                                       __ATOMIC_RELAXED, __HIP_MEMORY_SCOPE_AGENT);
            es[tid] = e;
        }
        __syncthreads();
        if (tid < 64) {
            float v[4]; int pv[4]; int n = 0;
            for (int q = 0; q < 4; q++) {
                int p = tid + 64 * q;
                if (p < P_) { pv[n] = p; v[n] = es[p]; n++; }
            }
            float m = -1e30f;
            for (int q = 0; q < n; q++) m = fmaxf(m, v[q]);
#pragma unroll
            for (int off = 32; off > 0; off >>= 1) m = fmaxf(m, __shfl_xor(m, off, 64));
            float ssum = 0.f;
            for (int q = 0; q < n; q++) { v[q] = expf(v[q] - m); ssum += v[q]; }
#pragma unroll
            for (int off = 32; off > 0; off >>= 1) ssum += __shfl_xor(ssum, off, 64);
            float rinv = 1.f / ssum;
            for (int q = 0; q < n; q++) al[pv[q]] = v[q] * rinv;
        }
        __syncthreads();

        // ---- alpha.G slice (from LDS)
        {
            int p0 = (kg < 4) ? kg * 25 : 100 + (kg - 4) * 24;
            int np = (kg < 4) ? 25 : 24;
            float pa[8] = {0.f,0.f,0.f,0.f,0.f,0.f,0.f,0.f};
#pragma unroll 4
            for (int i = 0; i < np; i++) {
                int p = p0 + i;
                float av = al[p];
                u16x8 gv = *(const u16x8*)&Gs[p][cg * 8];
#pragma unroll
                for (int q = 0; q < 8; q++) pa[q] += b2f(gv[q]) * av;
            }
#pragma unroll
            for (int q = 0; q < 8; q++) sred[kg][cg][q] = pa[q];
        }
        __syncthreads();
#pragma unroll
        for (int k2 = 0; k2 < 8; k2++) g += sred[k2][tid >> 3][tid & 7];
        gsh[tid] = g;
        __syncthreads();

        // ---- block-local pointwise LSTM for this block's 64 hidden units
        if (tid < 64) {
            int ri = tid >> 3, e = tid & 7;
            float gi = gsh[ri * 32 + e];
            float gf = gsh[ri * 32 + 8 + e];
            float gg = gsh[ri * 32 + 16 + e];
            float go = gsh[ri * 32 + 24 + e];
            float ig = 1.f / (1.f + expf(-gi));
            float fg = 1.f / (1.f + expf(-gf));
            float g_ = tanhf(gg);
            float og = 1.f / (1.f + expf(-go));
            c_reg = fg * c_reg + ig * g_;
            float hn = og * tanhf(c_reg);
            int u = 8 * s + 64 * ri + e;
            float* ho = hbuf + ((size_t)((t + 1) & 1) * 32 + b) * 512 + u;
            __hip_atomic_store(ho, hn, __ATOMIC_RELAXED, __HIP_MEMORY_SCOPE_AGENT);
            hseqB[(size_t)(t + 1) * 16384 + b * 512 + u] = bf_rne(hn);
        }
        __syncthreads();
        if (tid == 0)
            __hip_atomic_fetch_add(hcn, 1u,
                                   __ATOMIC_RELEASE, __HIP_MEMORY_SCOPE_AGENT);
    }
}

// ---------------------------------------------------------------------------
extern "C" void kernel_launch(void* const* d_in, const int* in_sizes, int n_in,
                              void* d_out, int out_size, void* d_ws, size_t ws_size,
                              hipStream_t stream)
{
    (void)in_sizes; (void)n_in; (void)out_size; (void)ws_size;
    const float* feat   = (const float*)d_in[0];
    const int*   caps   = (const int*)  d_in[1];
    const float* emb    = (const float*)d_in[2];
    const float* W_ih   = (const float*)d_in[3];
    const float* b_ih   = (const float*)d_in[4];
    const float* W_hh   = (const float*)d_in[5];
    const float* b_hh   = (const float*)d_in[6];
    const float* fc_W   = (const float*)d_in[7];
    const float* fc_b   = (const float*)d_in[8];
    const float* enc_W  = (const float*)d_in[9];
    const float* enc_b  = (const float*)d_in[10];
    const float* dec_W  = (const float*)d_in[11];
    const float* dec_b  = (const float*)d_in[12];
    const float* full_W = (const float*)d_in[13];
    const float* full_b = (const float*)d_in[14];
    float* out = (float*)d_out;

    // workspace carve (~90 MB), 128B-aligned chunks
    char* w = (char*)d_ws;
    ushort_t* featB = (ushort_t*)w;              w += 25690112;  // [6272][2048]
    ushort_t* encWB = (ushort_t*)w;              w += 2097152;   // [512][2048]
    ushort_t* fcWB  = (ushort_t*)w;              w += 10240000;  // [10000][512]
    ushort_t* decWB = (ushort_t*)w;              w += 524288;    // [512][512]
    ushort_t* WihCB = (ushort_t*)w;              w += 8388608;   // [2048][2048] (rows permuted)
    ushort_t* WihEB = (ushort_t*)w;              w += 2097152;   // [2048][512]  (rows permuted)
    ushort_t* WhhT  = (ushort_t*)w;              w += 2097152;   // [512][2048]  (cols permuted)
    ushort_t* XB    = (ushort_t*)w;              w += 655360;    // [640][512]
    ushort_t* encPT = (ushort_t*)w;              w += 6422528;   // [512][6272] a-major
    ushort_t* GB    = (ushort_t*)w;              w += 25690112;  // [6272][2048] (cols permuted)
    float*    xproj = (float*)w;                 w += 5242880;   // [640][2048]  (cols permuted)
    float*    bsum  = (float*)w;                 w += 8192;      // [2048] (permuted)
    float*    zbuf  = (float*)w;                 w += 8192;      // [2048]
    float*    hbuf  = (float*)w;                 w += 131072;    // [2][32][512]
    ushort_t* hseqB = (ushort_t*)w;              w += 688128;    // [21][32][512]
    unsigned* hcnt  = (unsigned*)w;              w += 4096;      // [32][32]
    unsigned* ecnt  = (unsigned*)w;              w += 4096;      // [32][32]
    float*    epartG= (float*)w;                 w += 204800;    // [32][8][200]

    // zero per-b sync counters (hcnt+ecnt adjacent; ws re-poisoned each replay)
    hipMemsetAsync(hcnt, 0, 8192, stream);

    // one-time converts / extracts / transposes / gathers / permutes (1 node)
    cvt_all_kernel<<<13125, 256, 0, stream>>>(
        feat, enc_W, fc_W, dec_W, W_ih, W_hh, emb, caps, b_ih, b_hh,
        featB, encWB, fcWB, decWB, WihCB, WihEB, WhhT, XB, bsum, zbuf);

    // enc_proj TRANSPOSED: [512,2048]x[6272,2048]^T -> encPT[a][b*196+p] bf16
    // (row bias enc_b[a] via mode 3)
    mfma_gemm_kernel<<<dim3(4, 49), 256, 0, stream>>>(
        encWB, featB, enc_b, encPT, nullptr, 2048, 6272, 3);

    // G = feat . W_ihC^T (rows of WihCB permuted -> GB cols permuted) bf16
    mfma_gemm_kernel<<<dim3(49, 16), 256, 0, stream>>>(
        featB, WihCB, zbuf, GB, nullptr, 2048, 2048, 0);

    // xproj = X . W_ihE^T + bsum (cols permuted to match)
    mfma_gemm_kernel<<<dim3(5, 16), 256, 0, stream>>>(
        XB, WihEB, bsum, nullptr, xproj, 512, 2048, 2);

    // persistent 20-step recurrent loop: 2 relaxed hops/step, de-dup attention
    persist_kernel<<<NBLK, 256, 0, stream>>>(
        hbuf, hseqB, encPT, decWB, dec_b, full_W, full_b,
        GB, WhhT, xproj, epartG, hcnt, ecnt);

    // batched vocab FC: [640,512]x[10000,512]^T -> out (f32, remapped rows)
    mfma_gemm_kernel<<<dim3(5, 79), 256, 0, stream>>>(
        hseqB + 16384, fcWB, fc_b, nullptr, out, 512, V_, 1);
}